// Round 1
// baseline (207.768 us; speedup 1.0000x reference)
//
#include <hip/hip_runtime.h>
#include <hip/hip_cooperative_groups.h>

namespace cg = cooperative_groups;

// Problem: N=4096 rows, D=64 feats, 10 classes.
// sym KL: sym_ij = 0.25*(H_i . Hp_j + s_i + s_j + det_ij + det_ji - 128)
// per-feature packed K layout (K=256):
//   H[r][4d+{0,1,2,3}] = { var+mu^2, -2mu, 1/var, mu/var }   (F0,F1,G0,G1)
// Hp is not stored: Hp[e] = H[pi(e)], pi swaps components c<->c+2 within each
// 4-group; on a lane's 8-element fragment it is the 32-bit register
// permutation [v1,v0,v3,v2].
//
// Storage is MFMA-FRAGMENT-MAJOR: Hf[tile=r>>5][k=e>>4][(r&31)*16 + (e&15)]
// so each k-step fragment load is 64 lanes x 16 B = 1 KB contiguous.
//
// R6 vs R5: single cooperative kernel (512 blocks, 2/CU co-resident) replaces
// the 3-dispatch pipeline. Phase 1 = per-row precompute (8 rows/block),
// grid.sync, phase 2 = 128x128 pair tiles (496 off-diag blocks x 1 tile,
// 16 blocks x 2 diagonal tiles), grid.sync, phase 3 = block-0 finalize.
// Tile math identical to R5 (verified, absmax 0.0). Fallback to the R5
// 3-kernel path if cooperative launch is rejected under graph capture.

#define N 4096
#define D 64
#define KH 256
#define MT 128             // pair block tile side
#define TILES2 32          // 4096/128
#define NOFF 496           // strict upper-tri tile pairs (it<jt)
#define NBLK2 528          // total tiles incl. 32 diagonal
#define GRID1 512          // cooperative grid: 2 blocks/CU x 256 CU
#define DET_EPS 1e-8f

typedef short bf16x8 __attribute__((ext_vector_type(8)));
typedef float f32x16 __attribute__((ext_vector_type(16)));

// ws byte layout
#define WS_H    0                       // ushort[N/32][16][512] = 2 MB (frag-major)
#define WS_PSL  (N * KH * 2)            // float4[N] = 64 KB
#define WS_PART (WS_PSL + N * 16)       // float[2*NBLK2]

static __device__ __forceinline__ unsigned short f2bf(float x) {
  // round-to-nearest-even bf16
  unsigned int u = __float_as_uint(x);
  unsigned int r = (u + 0x7FFFu + ((u >> 16) & 1u)) >> 16;
  return (unsigned short)r;
}

static __device__ __forceinline__ f32x16 mfma_bf16(bf16x8 a, bf16x8 b, f32x16 c) {
  return __builtin_amdgcn_mfma_f32_32x32x16_bf16(a, b, c, 0, 0, 0);
}

// ---------------------------------------------------------------------------
// Per-row precompute for row r; caller supplies one wave (lane = feature d).
// Stores Hf (frag-major) and PSL = {p, 1/(p+eps), 0.25*s-16, label}.
static __device__ __forceinline__ void row_precompute(
    int r, int lane, const float* __restrict__ mu, const float* __restrict__ var,
    const int* __restrict__ labels,
    unsigned short* __restrict__ Hf, float4* __restrict__ PSL) {
  const float m = mu[r * D + lane];
  const float v = var[r * D + lane];
  const float g0 = 1.0f / v;
  const float f0 = v + m * m;
  const float f1 = -2.0f * m;
  const float g1 = m * g0;

  // element e = 4*d + c; frag-major idx:
  //   (r>>5)*8192 + (e>>4)*512 + (r&31)*16 + (e&15)
  const size_t base = (size_t)(r >> 5) * 8192 + (size_t)(lane >> 2) * 512
                      + (size_t)(r & 31) * 16 + (size_t)(lane & 3) * 4;
  *(ushort4*)&Hf[base] = make_ushort4(f2bf(f0), f2bf(f1), f2bf(g0), f2bf(g1));

  // wave reductions: p = prod var, s = sum mu^2/var
  float p = v;
  float s = m * m * g0;
  #pragma unroll
  for (int off = 1; off < 64; off <<= 1) {
    p *= __shfl_xor(p, off);
    s += __shfl_xor(s, off);
  }
  if (lane == 0) {
    PSL[r] = make_float4(p, 1.0f / (p + DET_EPS), 0.25f * s - 16.0f,
                         (float)labels[r]);
  }
}

// ---------------------------------------------------------------------------
// One 128x128 pair tile (it, jt), it <= jt; block-wide. 4 waves; wave w =
// quadrant (sr=w>>1, sc=w&1), each wave a 2x2 grid of 32x32 MFMA subtiles.
// B fragments derived from H via in-register component swap (see header).
// Writes partial[slot] / partial[NBLK2+slot].
static __device__ __forceinline__ void do_tile(
    int it, int jt, int slot,
    const unsigned short* __restrict__ Hf,
    const float4* __restrict__ PSL, float* __restrict__ partial) {
  __shared__ float4 sPi[128];
  __shared__ float4 sPj[128];
  __shared__ float red[8];

  const int i0 = it * MT, j0 = jt * MT;
  const int t = threadIdx.x;
  const int lane = t & 63;
  const int w = t >> 6;               // 0..3
  const int sr = w >> 1, sc = w & 1;  // 64x64 quadrant of the 128x128 block

  // protect previous users of sPi/sPj/red (second tile of a diagonal pair)
  __syncthreads();
  if (t < 128) sPi[t] = PSL[i0 + t];
  else sPj[t - 128] = PSL[j0 + t - 128];
  __syncthreads();

  const int l31 = lane & 31;
  const int slot_f = l31 * 16 + (lane >> 5) * 8;  // frag-major lane slot
  const unsigned short* pa = Hf + (size_t)(i0 / 32 + sr * 2) * 8192 + slot_f;
  const unsigned short* pb = Hf + (size_t)(j0 / 32 + sc * 2) * 8192 + slot_f;

  // diagonal big-tile: quadrant (1,0) is entirely below the diagonal
  const bool active = !(it == jt && w == 2);

  f32x16 C00 = {}, C01 = {}, C10 = {}, C11 = {};
  float pos = 0.0f, neg = 0.0f;

  if (active) {
    #pragma unroll 4
    for (int k = 0; k < 16; ++k) {
      const bf16x8 a0 = *(const bf16x8*)(pa + k * 512);
      const bf16x8 a1 = *(const bf16x8*)(pa + 8192 + k * 512);
      const bf16x8 c0 = *(const bf16x8*)(pb + k * 512);
      const bf16x8 c1 = *(const bf16x8*)(pb + 8192 + k * 512);
      // pi(e): swap component pairs -> 32-bit reg perm [v1,v0,v3,v2]
      const bf16x8 b0 = __builtin_shufflevector(c0, c0, 2, 3, 0, 1, 6, 7, 4, 5);
      const bf16x8 b1 = __builtin_shufflevector(c1, c1, 2, 3, 0, 1, 6, 7, 4, 5);
      C00 = mfma_bf16(a0, b0, C00);
      C01 = mfma_bf16(a0, b1, C01);
      C10 = mfma_bf16(a1, b0, C10);
      C11 = mfma_bf16(a1, b1, C11);
    }

    // epilogue: C/D layout col=lane&31, row=(r&3)+8*(r>>2)+4*(lane>>5)
    const int rbase = 4 * (lane >> 5);
    #pragma unroll
    for (int mn = 0; mn < 4; ++mn) {
      const int m = mn >> 1, n = mn & 1;
      const f32x16 C = (mn == 0) ? C00 : (mn == 1) ? C01 : (mn == 2) ? C10 : C11;
      const int jloc = (sc * 2 + n) * 32 + l31;
      const int j = j0 + jloc;
      const float4 pj = sPj[jloc];
      #pragma unroll
      for (int r = 0; r < 16; ++r) {
        const int row = (r & 3) + 8 * (r >> 2) + rbase;
        const int iloc = (sr * 2 + m) * 32 + row;
        const int i = i0 + iloc;
        if (i < j) {                   // strict upper triangle only
          const float4 pi = sPi[iloc];
          const float det = pj.x * pi.y + pi.x * pj.y;
          const float sym = 0.25f * (C[r] + det) + pi.z + pj.z;
          const float sig = __builtin_amdgcn_rcpf(1.0f + __expf(-sym));
          if (pi.w == pj.w) pos += sig; else neg += sig;
        }
      }
    }
  }

  // wave reduce -> LDS -> per-tile private slot store (no atomics)
  #pragma unroll
  for (int off = 32; off > 0; off >>= 1) {
    pos += __shfl_down(pos, off);
    neg += __shfl_down(neg, off);
  }
  if (lane == 0) { red[w] = pos; red[4 + w] = neg; }
  __syncthreads();
  if (t == 0) {
    partial[slot]         = red[0] + red[1] + red[2] + red[3];
    partial[NBLK2 + slot] = red[4] + red[5] + red[6] + red[7];
  }
}

// ---------------------------------------------------------------------------
// Fused cooperative kernel: precompute -> grid.sync -> pair tiles ->
// grid.sync -> block-0 finalize. 512 blocks (2/CU).
__global__ __launch_bounds__(256, 2) void fused_kernel(
    const float* __restrict__ mu, const float* __restrict__ var,
    const int* __restrict__ labels,
    unsigned short* __restrict__ Hf, float4* __restrict__ PSL,
    float* __restrict__ partial, float* __restrict__ out) {
  const int bid = (int)blockIdx.x;
  const int t = (int)threadIdx.x;
  const int lane = t & 63;
  const int w = t >> 6;

  // ---- phase 1: per-row precompute, 8 rows per block (4 waves x 2) ----
  #pragma unroll
  for (int itr = 0; itr < 2; ++itr)
    row_precompute(bid * 8 + itr * 4 + w, lane, mu, var, labels, Hf, PSL);

  cg::this_grid().sync();

  // ---- phase 2: pair tiles ----
  if (bid < NOFF) {
    // strict upper-tri decode: bid -> (it, jt), it < jt; f(it)=31it-it(it-1)/2
    int it = (int)((63.0f - sqrtf(3969.0f - 8.0f * (float)bid)) * 0.5f);
    while (it > 0 && bid < 31 * it - it * (it - 1) / 2) --it;
    while (bid >= 31 * (it + 1) - (it + 1) * it / 2) ++it;
    const int jt = it + 1 + (bid - (31 * it - it * (it - 1) / 2));
    do_tile(it, jt, bid, Hf, PSL, partial);
  } else {
    // 16 blocks each take two cheap diagonal tiles (~0.7x cost each)
    const int dd = bid - NOFF;
    do_tile(2 * dd,     2 * dd,     NOFF + 2 * dd,     Hf, PSL, partial);
    do_tile(2 * dd + 1, 2 * dd + 1, NOFF + 2 * dd + 1, Hf, PSL, partial);
  }

  cg::this_grid().sync();

  // ---- phase 3: finalize on block 0 ----
  if (bid == 0) {
    __shared__ float redp[4], redn[4];
    float p = 0.0f, n = 0.0f;
    for (int i = t; i < NBLK2; i += 256) {
      p += partial[i];
      n += partial[NBLK2 + i];
    }
    #pragma unroll
    for (int off = 32; off > 0; off >>= 1) {
      p += __shfl_down(p, off);
      n += __shfl_down(n, off);
    }
    if (lane == 0) { redp[w] = p; redn[w] = n; }
    __syncthreads();
    if (t == 0) {
      const float pos = 2.0f * (redp[0] + redp[1] + redp[2] + redp[3]);
      const float neg = 2.0f * (redn[0] + redn[1] + redn[2] + redn[3]);
      out[0] = pos * (1.0f / 16777216.0f);  // mean over N*N = 2^24
      out[1] = neg * (1.0f / 16777216.0f);
      out[2] = pos;
      out[3] = neg;
    }
  }
}

// ---------------------------------------------------------------------------
// Fallback path (R5 structure) in case cooperative launch is rejected
// under graph capture.
__global__ __launch_bounds__(256) void precompute_kernel(
    const float* __restrict__ mu, const float* __restrict__ var,
    const int* __restrict__ labels,
    unsigned short* __restrict__ Hf, float4* __restrict__ PSL) {
  const int t = threadIdx.x;
  row_precompute(blockIdx.x * 4 + (t >> 6), t & 63, mu, var, labels, Hf, PSL);
}

__global__ __launch_bounds__(256, 2) void pair_kernel(
    const unsigned short* __restrict__ Hf,
    const float4* __restrict__ PSL, float* __restrict__ partial) {
  // inclusive-triangle decode: block L -> (it, jt), it <= jt
  int L = (int)blockIdx.x;
  int it = (int)(32.5f - sqrtf(32.5f * 32.5f - 2.0f * (float)L));
  while (it > 0 && L < it * TILES2 - it * (it - 1) / 2) --it;
  while (L >= (it + 1) * TILES2 - (it + 1) * it / 2) ++it;
  const int jt = it + (L - (it * TILES2 - it * (it - 1) / 2));
  do_tile(it, jt, L, Hf, PSL, partial);
}

__global__ __launch_bounds__(256) void finalize_kernel(
    const float* __restrict__ partial, float* __restrict__ out) {
  __shared__ float redp[4], redn[4];
  const int t = threadIdx.x;
  const int lane = t & 63, w = t >> 6;
  float p = 0.0f, n = 0.0f;
  for (int i = t; i < NBLK2; i += 256) {
    p += partial[i];
    n += partial[NBLK2 + i];
  }
  #pragma unroll
  for (int off = 32; off > 0; off >>= 1) {
    p += __shfl_down(p, off);
    n += __shfl_down(n, off);
  }
  if (lane == 0) { redp[w] = p; redn[w] = n; }
  __syncthreads();
  if (t == 0) {
    const float pos = 2.0f * (redp[0] + redp[1] + redp[2] + redp[3]);
    const float neg = 2.0f * (redn[0] + redn[1] + redn[2] + redn[3]);
    out[0] = pos * (1.0f / 16777216.0f);
    out[1] = neg * (1.0f / 16777216.0f);
    out[2] = pos;
    out[3] = neg;
  }
}

extern "C" void kernel_launch(void* const* d_in, const int* in_sizes, int n_in,
                              void* d_out, int out_size, void* d_ws, size_t ws_size,
                              hipStream_t stream) {
  const float* mu = (const float*)d_in[0];
  const float* var = (const float*)d_in[1];
  const int* labels = (const int*)d_in[2];
  float* out = (float*)d_out;
  char* ws = (char*)d_ws;

  unsigned short* Hf = (unsigned short*)(ws + WS_H);
  float4* PSL = (float4*)(ws + WS_PSL);
  float* partial = (float*)(ws + WS_PART);

  void* args[] = {(void*)&mu, (void*)&var, (void*)&labels,
                  (void*)&Hf, (void*)&PSL, (void*)&partial, (void*)&out};
  hipError_t e = hipLaunchCooperativeKernel((const void*)fused_kernel,
                                            dim3(GRID1), dim3(256), args, 0,
                                            stream);
  if (e != hipSuccess) {
    // 3-dispatch fallback (identical math)
    precompute_kernel<<<dim3(N / 4), dim3(256), 0, stream>>>(mu, var, labels, Hf, PSL);
    pair_kernel<<<dim3(NBLK2), dim3(256), 0, stream>>>(Hf, PSL, partial);
    finalize_kernel<<<dim3(1), dim3(256), 0, stream>>>(partial, out);
  }
}

// Round 2
// 107.673 us; speedup vs baseline: 1.9296x; 1.9296x over previous
//
#include <hip/hip_runtime.h>

// Problem: N=4096 rows, D=64 feats, 10 classes.
// sym KL: sym_ij = 0.25*(H_i . Hp_j + s_i + s_j + det_ij + det_ji - 128)
// per-feature packed K layout (K=256):
//   H[r][4d+{0,1,2,3}] = { var+mu^2, -2mu, 1/var, mu/var }   (F0,F1,G0,G1)
// Hp is not stored: Hp[e] = H[pi(e)], pi swaps components c<->c+2 within each
// 4-group; on a lane's 8-element fragment it is the 32-bit register
// permutation [v1,v0,v3,v2].
//
// Storage is MFMA-FRAGMENT-MAJOR: Hf[tile=r>>5][k=e>>4][(r&31)*16 + (e&15)]
// so each k-step fragment load is 64 lanes x 16 B = 1 KB contiguous.
//
// R7 vs R5/R6: cooperative fusion REVERTED (grid.sync spun for ~135 us with
// all pipes idle -- R6 post-mortem). Instead:
//   * 512-block balanced grid (496 off-diag tiles x 1 block, 16 blocks take
//     two cheap diagonal tiles each) -- kills R5's 16-block second round
//     (2.0x tail -> ~1.4x).
//   * finalize fused into the pair kernel via last-block-done protocol
//     (atomicExch partials + __threadfence + counter; final 528-sum uses the
//     same fixed index order as the old finalize kernel -> deterministic).
//   * epilogue branch i<j removed for off-diag tiles (template<DIAG>).

#define N 4096
#define D 64
#define KH 256
#define MT 128             // pair block tile side
#define TILES2 32          // 4096/128
#define NOFF 496           // strict upper-tri tile pairs (it<jt)
#define NBLK2 528          // total tiles incl. 32 diagonal
#define GRID2 512          // pair grid: 2 blocks/CU x 256 CU, one round
#define DET_EPS 1e-8f

typedef short bf16x8 __attribute__((ext_vector_type(8)));
typedef float f32x16 __attribute__((ext_vector_type(16)));

// ws byte layout
#define WS_H    0                       // ushort[N/32][16][512] = 2 MB (frag-major)
#define WS_PSL  (N * KH * 2)            // float4[N] = 64 KB
#define WS_PART (WS_PSL + N * 16)       // float[2*NBLK2]
#define WS_CNT  (WS_PART + 2 * NBLK2 * 4)  // unsigned int completion counter

static __device__ __forceinline__ unsigned short f2bf(float x) {
  // round-to-nearest-even bf16
  unsigned int u = __float_as_uint(x);
  unsigned int r = (u + 0x7FFFu + ((u >> 16) & 1u)) >> 16;
  return (unsigned short)r;
}

static __device__ __forceinline__ f32x16 mfma_bf16(bf16x8 a, bf16x8 b, f32x16 c) {
  return __builtin_amdgcn_mfma_f32_32x32x16_bf16(a, b, c, 0, 0, 0);
}

// ---------------------------------------------------------------------------
// Kernel 1: per-row precompute. 1024 blocks x 256 thr; one wave per row.
// Stores Hf (frag-major) and PSL = {p, 1/(p+eps), 0.25*s-16, label}.
// Block 0 also zero-inits the completion counter for kernel 2.
__global__ __launch_bounds__(256) void precompute_kernel(
    const float* __restrict__ mu, const float* __restrict__ var,
    const int* __restrict__ labels,
    unsigned short* __restrict__ Hf, float4* __restrict__ PSL,
    unsigned int* __restrict__ counter) {
  const int t = threadIdx.x;
  const int lane = t & 63;   // feature d
  const int w = t >> 6;
  const int r = blockIdx.x * 4 + w;

  if (blockIdx.x == 0 && t == 0) *counter = 0u;  // ws is poisoned each iter

  const float m = mu[r * D + lane];
  const float v = var[r * D + lane];
  const float g0 = 1.0f / v;
  const float f0 = v + m * m;
  const float f1 = -2.0f * m;
  const float g1 = m * g0;

  // element e = 4*d + c; frag-major idx:
  //   (r>>5)*8192 + (e>>4)*512 + (r&31)*16 + (e&15)
  const size_t base = (size_t)(r >> 5) * 8192 + (size_t)(lane >> 2) * 512
                      + (size_t)(r & 31) * 16 + (size_t)(lane & 3) * 4;
  *(ushort4*)&Hf[base] = make_ushort4(f2bf(f0), f2bf(f1), f2bf(g0), f2bf(g1));

  // wave reductions: p = prod var, s = sum mu^2/var
  float p = v;
  float s = m * m * g0;
  #pragma unroll
  for (int off = 1; off < 64; off <<= 1) {
    p *= __shfl_xor(p, off);
    s += __shfl_xor(s, off);
  }
  if (lane == 0) {
    PSL[r] = make_float4(p, 1.0f / (p + DET_EPS), 0.25f * s - 16.0f,
                         (float)labels[r]);
  }
}

// ---------------------------------------------------------------------------
// One 128x128 pair tile (it, jt), it <= jt; block-wide. 4 waves; wave w =
// quadrant (sr=w>>1, sc=w&1), each wave a 2x2 grid of 32x32 MFMA subtiles.
// B fragments derived from H via in-register component swap (see header).
// Writes partial[slot] / partial[NBLK2+slot] via device-coherent atomicExch.
template <bool DIAG>
static __device__ __forceinline__ void do_tile(
    int it, int jt, int slot,
    const unsigned short* __restrict__ Hf,
    const float4* __restrict__ PSL, float* __restrict__ partial,
    float4* sPi, float4* sPj, float* red) {
  const int i0 = it * MT, j0 = jt * MT;
  const int t = threadIdx.x;
  const int lane = t & 63;
  const int w = t >> 6;               // 0..3
  const int sr = w >> 1, sc = w & 1;  // 64x64 quadrant of the 128x128 block

  // protect previous users of sPi/sPj/red (second tile of a diagonal pair)
  __syncthreads();
  if (t < 128) sPi[t] = PSL[i0 + t];
  else sPj[t - 128] = PSL[j0 + t - 128];
  __syncthreads();

  const int l31 = lane & 31;
  const int slot_f = l31 * 16 + (lane >> 5) * 8;  // frag-major lane slot
  const unsigned short* pa = Hf + (size_t)(i0 / 32 + sr * 2) * 8192 + slot_f;
  const unsigned short* pb = Hf + (size_t)(j0 / 32 + sc * 2) * 8192 + slot_f;

  // diagonal big-tile: quadrant (1,0) is entirely below the diagonal
  const bool active = !(DIAG && w == 2);

  f32x16 C00 = {}, C01 = {}, C10 = {}, C11 = {};
  float pos = 0.0f, neg = 0.0f;

  if (active) {
    #pragma unroll 4
    for (int k = 0; k < 16; ++k) {
      const bf16x8 a0 = *(const bf16x8*)(pa + k * 512);
      const bf16x8 a1 = *(const bf16x8*)(pa + 8192 + k * 512);
      const bf16x8 c0 = *(const bf16x8*)(pb + k * 512);
      const bf16x8 c1 = *(const bf16x8*)(pb + 8192 + k * 512);
      // pi(e): swap component pairs -> 32-bit reg perm [v1,v0,v3,v2]
      const bf16x8 b0 = __builtin_shufflevector(c0, c0, 2, 3, 0, 1, 6, 7, 4, 5);
      const bf16x8 b1 = __builtin_shufflevector(c1, c1, 2, 3, 0, 1, 6, 7, 4, 5);
      C00 = mfma_bf16(a0, b0, C00);
      C01 = mfma_bf16(a0, b1, C01);
      C10 = mfma_bf16(a1, b0, C10);
      C11 = mfma_bf16(a1, b1, C11);
    }

    // epilogue: C/D layout col=lane&31, row=(r&3)+8*(r>>2)+4*(lane>>5)
    const int rbase = 4 * (lane >> 5);
    #pragma unroll
    for (int mn = 0; mn < 4; ++mn) {
      const int m = mn >> 1, n = mn & 1;
      const f32x16 C = (mn == 0) ? C00 : (mn == 1) ? C01 : (mn == 2) ? C10 : C11;
      const int jloc = (sc * 2 + n) * 32 + l31;
      const float4 pj = sPj[jloc];
      #pragma unroll
      for (int r = 0; r < 16; ++r) {
        const int row = (r & 3) + 8 * (r >> 2) + rbase;
        const int iloc = (sr * 2 + m) * 32 + row;
        // off-diag big tiles: i0+127 < j0, so i<j holds for every element
        if (!DIAG || (i0 + iloc) < (j0 + jloc)) {
          const float4 pi = sPi[iloc];
          const float det = pj.x * pi.y + pi.x * pj.y;
          const float sym = 0.25f * (C[r] + det) + pi.z + pj.z;
          const float sig = __builtin_amdgcn_rcpf(1.0f + __expf(-sym));
          if (pi.w == pj.w) pos += sig; else neg += sig;
        }
      }
    }
  }

  // wave reduce -> LDS -> per-tile private slot store (device-coherent)
  #pragma unroll
  for (int off = 32; off > 0; off >>= 1) {
    pos += __shfl_down(pos, off);
    neg += __shfl_down(neg, off);
  }
  if (lane == 0) { red[w] = pos; red[4 + w] = neg; }
  __syncthreads();
  if (t == 0) {
    atomicExch(&partial[slot],         red[0] + red[1] + red[2] + red[3]);
    atomicExch(&partial[NBLK2 + slot], red[4] + red[5] + red[6] + red[7]);
  }
}

// ---------------------------------------------------------------------------
// Kernel 2: 512 balanced blocks of pair tiles + last-block finalize.
// Full-grid sums = 2 * triangle sums (sym matrix, diag excluded).
__global__ __launch_bounds__(256, 2) void pair_finalize_kernel(
    const unsigned short* __restrict__ Hf,
    const float4* __restrict__ PSL, float* __restrict__ partial,
    unsigned int* __restrict__ counter, float* __restrict__ out) {
  __shared__ float4 sPi[128];
  __shared__ float4 sPj[128];
  __shared__ float red[8];
  __shared__ unsigned int sOrd;

  const int bid = (int)blockIdx.x;
  const int t = (int)threadIdx.x;

  if (bid < NOFF) {
    // strict upper-tri decode: bid -> (it, jt), it < jt; f(it)=31it-it(it-1)/2
    int it = (int)((63.0f - sqrtf(3969.0f - 8.0f * (float)bid)) * 0.5f);
    while (it > 0 && bid < 31 * it - it * (it - 1) / 2) --it;
    while (bid >= 31 * (it + 1) - (it + 1) * it / 2) ++it;
    const int jt = it + 1 + (bid - (31 * it - it * (it - 1) / 2));
    do_tile<false>(it, jt, bid, Hf, PSL, partial, sPi, sPj, red);
  } else {
    // 16 blocks each take two cheap diagonal tiles (~0.7x cost each)
    const int dd = bid - NOFF;
    do_tile<true>(2 * dd,     2 * dd,     NOFF + 2 * dd,     Hf, PSL, partial,
                  sPi, sPj, red);
    do_tile<true>(2 * dd + 1, 2 * dd + 1, NOFF + 2 * dd + 1, Hf, PSL, partial,
                  sPi, sPj, red);
  }

  // last-block-done protocol (device-scope; safe across XCDs per G16)
  __threadfence();
  if (t == 0) sOrd = atomicAdd(counter, 1u);
  __syncthreads();
  if (sOrd == GRID2 - 1) {
    __shared__ float redp[4], redn[4];
    const int lane = t & 63, w = t >> 6;
    float p = 0.0f, n = 0.0f;
    // atomic loads (device-coherent); fixed index order -> deterministic sum
    for (int i = t; i < NBLK2; i += 256) {
      p += atomicAdd(&partial[i], 0.0f);
      n += atomicAdd(&partial[NBLK2 + i], 0.0f);
    }
    #pragma unroll
    for (int off = 32; off > 0; off >>= 1) {
      p += __shfl_down(p, off);
      n += __shfl_down(n, off);
    }
    if (lane == 0) { redp[w] = p; redn[w] = n; }
    __syncthreads();
    if (t == 0) {
      const float pos = 2.0f * (redp[0] + redp[1] + redp[2] + redp[3]);
      const float neg = 2.0f * (redn[0] + redn[1] + redn[2] + redn[3]);
      out[0] = pos * (1.0f / 16777216.0f);  // mean over N*N = 2^24
      out[1] = neg * (1.0f / 16777216.0f);
      out[2] = pos;
      out[3] = neg;
    }
  }
}

extern "C" void kernel_launch(void* const* d_in, const int* in_sizes, int n_in,
                              void* d_out, int out_size, void* d_ws, size_t ws_size,
                              hipStream_t stream) {
  const float* mu = (const float*)d_in[0];
  const float* var = (const float*)d_in[1];
  const int* labels = (const int*)d_in[2];
  float* out = (float*)d_out;
  char* ws = (char*)d_ws;

  unsigned short* Hf = (unsigned short*)(ws + WS_H);
  float4* PSL = (float4*)(ws + WS_PSL);
  float* partial = (float*)(ws + WS_PART);
  unsigned int* counter = (unsigned int*)(ws + WS_CNT);

  precompute_kernel<<<dim3(N / 4), dim3(256), 0, stream>>>(mu, var, labels, Hf,
                                                           PSL, counter);
  pair_finalize_kernel<<<dim3(GRID2), dim3(256), 0, stream>>>(Hf, PSL, partial,
                                                              counter, out);
}

// Round 3
// 83.876 us; speedup vs baseline: 2.4771x; 1.2837x over previous
//
#include <hip/hip_runtime.h>

// Problem: N=4096 rows, D=64 feats, 10 classes.
// sym KL: sym_ij = 0.25*(H_i . Hp_j + s_i + s_j + det_ij + det_ji - 128)
// per-feature packed K layout (K=256):
//   H[r][4d+{0,1,2,3}] = { var+mu^2, -2mu, 1/var, mu/var }   (F0,F1,G0,G1)
// Hp is not stored: Hp[e] = H[pi(e)], pi swaps components c<->c+2 within each
// 4-group; on a lane's 8-element fragment it is the 32-bit register
// permutation [v1,v0,v3,v2].
//
// Storage is MFMA-FRAGMENT-MAJOR: Hf[tile=r>>5][k=e>>4][(r&31)*16 + (e&15)]
// so each k-step fragment load is 64 lanes x 16 B = 1 KB contiguous.
//
// R8 vs R7: device-scope last-block protocol REVERTED (R7 post-mortem: 512
// blocks' fence + hot-line atomic rendezvous cost ~35-45 us serialized at the
// cross-XCD coherence point; R6's grid.sync = same mechanism x2.7). Back to
// plain stores + tiny finalize dispatch (R5 semantics, deterministic).
// Kept from R7: balanced 512-block grid (496 off-diag x 1 tile, 16 x 2 diag
// tiles), template<DIAG> branch-free epilogue.
// NEW: K-loop software pipeline -- chunk-2 double-buffered register prefetch,
// fully unrolled (compile-time indices only). R7's VGPR=68 proved the
// compiler serialized load->wait->MFMA (~250 cy L2 latency exposed per step,
// MfmaUtil 3%); explicit prefetch puts ~8 KB/wave in flight (~64 KB/CU >>
// 13 KB needed for L2-BW saturation).

#define N 4096
#define D 64
#define KH 256
#define MT 128             // pair block tile side
#define TILES2 32          // 4096/128
#define NOFF 496           // strict upper-tri tile pairs (it<jt)
#define NBLK2 528          // total tiles incl. 32 diagonal
#define GRID2 512          // pair grid: 2 blocks/CU x 256 CU, one round
#define DET_EPS 1e-8f

typedef short bf16x8 __attribute__((ext_vector_type(8)));
typedef float f32x16 __attribute__((ext_vector_type(16)));

// ws byte layout
#define WS_H    0                       // ushort[N/32][16][512] = 2 MB (frag-major)
#define WS_PSL  (N * KH * 2)            // float4[N] = 64 KB
#define WS_PART (WS_PSL + N * 16)       // float[2*NBLK2]

static __device__ __forceinline__ unsigned short f2bf(float x) {
  // round-to-nearest-even bf16
  unsigned int u = __float_as_uint(x);
  unsigned int r = (u + 0x7FFFu + ((u >> 16) & 1u)) >> 16;
  return (unsigned short)r;
}

static __device__ __forceinline__ f32x16 mfma_bf16(bf16x8 a, bf16x8 b, f32x16 c) {
  return __builtin_amdgcn_mfma_f32_32x32x16_bf16(a, b, c, 0, 0, 0);
}

// ---------------------------------------------------------------------------
// Kernel 1: per-row precompute. 1024 blocks x 256 thr; one wave per row.
// Stores Hf (frag-major) and PSL = {p, 1/(p+eps), 0.25*s-16, label}.
__global__ __launch_bounds__(256) void precompute_kernel(
    const float* __restrict__ mu, const float* __restrict__ var,
    const int* __restrict__ labels,
    unsigned short* __restrict__ Hf, float4* __restrict__ PSL) {
  const int t = threadIdx.x;
  const int lane = t & 63;   // feature d
  const int w = t >> 6;
  const int r = blockIdx.x * 4 + w;

  const float m = mu[r * D + lane];
  const float v = var[r * D + lane];
  const float g0 = 1.0f / v;
  const float f0 = v + m * m;
  const float f1 = -2.0f * m;
  const float g1 = m * g0;

  // element e = 4*d + c; frag-major idx:
  //   (r>>5)*8192 + (e>>4)*512 + (r&31)*16 + (e&15)
  const size_t base = (size_t)(r >> 5) * 8192 + (size_t)(lane >> 2) * 512
                      + (size_t)(r & 31) * 16 + (size_t)(lane & 3) * 4;
  *(ushort4*)&Hf[base] = make_ushort4(f2bf(f0), f2bf(f1), f2bf(g0), f2bf(g1));

  // wave reductions: p = prod var, s = sum mu^2/var
  float p = v;
  float s = m * m * g0;
  #pragma unroll
  for (int off = 1; off < 64; off <<= 1) {
    p *= __shfl_xor(p, off);
    s += __shfl_xor(s, off);
  }
  if (lane == 0) {
    PSL[r] = make_float4(p, 1.0f / (p + DET_EPS), 0.25f * s - 16.0f,
                         (float)labels[r]);
  }
}

// ---------------------------------------------------------------------------
// One 128x128 pair tile (it, jt), it <= jt; block-wide. 4 waves; wave w =
// quadrant (sr=w>>1, sc=w&1), each wave a 2x2 grid of 32x32 MFMA subtiles.
// B fragments derived from H via in-register component swap (see header).
// K-loop: chunk-2 double-buffered register prefetch (all indices static
// after full unroll -- no scratch).
template <bool DIAG>
static __device__ __forceinline__ void do_tile(
    int it, int jt, int slot,
    const unsigned short* __restrict__ Hf,
    const float4* __restrict__ PSL, float* __restrict__ partial,
    float4* sPi, float4* sPj, float* red) {
  const int i0 = it * MT, j0 = jt * MT;
  const int t = threadIdx.x;
  const int lane = t & 63;
  const int w = t >> 6;               // 0..3
  const int sr = w >> 1, sc = w & 1;  // 64x64 quadrant of the 128x128 block

  // protect previous users of sPi/sPj/red (second tile of a diagonal pair)
  __syncthreads();
  if (t < 128) sPi[t] = PSL[i0 + t];
  else sPj[t - 128] = PSL[j0 + t - 128];
  __syncthreads();

  const int l31 = lane & 31;
  const int slot_f = l31 * 16 + (lane >> 5) * 8;  // frag-major lane slot
  const unsigned short* pa = Hf + (size_t)(i0 / 32 + sr * 2) * 8192 + slot_f;
  const unsigned short* pb = Hf + (size_t)(j0 / 32 + sc * 2) * 8192 + slot_f;

  // diagonal big-tile: quadrant (1,0) is entirely below the diagonal
  const bool active = !(DIAG && w == 2);

  f32x16 C00 = {}, C01 = {}, C10 = {}, C11 = {};
  float pos = 0.0f, neg = 0.0f;

  if (active) {
    // ---- software-pipelined K-loop: 8 chunks of 2 k-steps, 2 reg buffers --
    bf16x8 bA0[2][2], bA1[2][2], bC0[2][2], bC1[2][2];
    #pragma unroll
    for (int s = 0; s < 2; ++s) {           // preload chunk 0 (k=0,1)
      bA0[0][s] = *(const bf16x8*)(pa + s * 512);
      bA1[0][s] = *(const bf16x8*)(pa + 8192 + s * 512);
      bC0[0][s] = *(const bf16x8*)(pb + s * 512);
      bC1[0][s] = *(const bf16x8*)(pb + 8192 + s * 512);
    }
    #pragma unroll
    for (int c = 0; c < 8; ++c) {           // fully unrolled: cur/nxt static
      const int cur = c & 1, nxt = cur ^ 1;
      if (c < 7) {                          // prefetch chunk c+1 (k=2c+2,2c+3)
        #pragma unroll
        for (int s = 0; s < 2; ++s) {
          const int k = (c + 1) * 2 + s;
          bA0[nxt][s] = *(const bf16x8*)(pa + k * 512);
          bA1[nxt][s] = *(const bf16x8*)(pa + 8192 + k * 512);
          bC0[nxt][s] = *(const bf16x8*)(pb + k * 512);
          bC1[nxt][s] = *(const bf16x8*)(pb + 8192 + k * 512);
        }
      }
      #pragma unroll
      for (int s = 0; s < 2; ++s) {
        // pi(e): swap component pairs -> 32-bit reg perm [v1,v0,v3,v2]
        const bf16x8 b0 =
            __builtin_shufflevector(bC0[cur][s], bC0[cur][s], 2, 3, 0, 1, 6, 7, 4, 5);
        const bf16x8 b1 =
            __builtin_shufflevector(bC1[cur][s], bC1[cur][s], 2, 3, 0, 1, 6, 7, 4, 5);
        C00 = mfma_bf16(bA0[cur][s], b0, C00);
        C01 = mfma_bf16(bA0[cur][s], b1, C01);
        C10 = mfma_bf16(bA1[cur][s], b0, C10);
        C11 = mfma_bf16(bA1[cur][s], b1, C11);
      }
    }

    // epilogue: C/D layout col=lane&31, row=(r&3)+8*(r>>2)+4*(lane>>5)
    const int rbase = 4 * (lane >> 5);
    #pragma unroll
    for (int mn = 0; mn < 4; ++mn) {
      const int m = mn >> 1, n = mn & 1;
      const f32x16 C = (mn == 0) ? C00 : (mn == 1) ? C01 : (mn == 2) ? C10 : C11;
      const int jloc = (sc * 2 + n) * 32 + l31;
      const float4 pj = sPj[jloc];
      #pragma unroll
      for (int r = 0; r < 16; ++r) {
        const int row = (r & 3) + 8 * (r >> 2) + rbase;
        const int iloc = (sr * 2 + m) * 32 + row;
        // off-diag big tiles: i0+127 < j0, so i<j holds for every element
        if (!DIAG || (i0 + iloc) < (j0 + jloc)) {
          const float4 pi = sPi[iloc];
          const float det = pj.x * pi.y + pi.x * pj.y;
          const float sym = 0.25f * (C[r] + det) + pi.z + pj.z;
          const float sig = __builtin_amdgcn_rcpf(1.0f + __expf(-sym));
          if (pi.w == pj.w) pos += sig; else neg += sig;
        }
      }
    }
  }

  // wave reduce -> LDS -> per-tile private slot store (no atomics)
  #pragma unroll
  for (int off = 32; off > 0; off >>= 1) {
    pos += __shfl_down(pos, off);
    neg += __shfl_down(neg, off);
  }
  if (lane == 0) { red[w] = pos; red[4 + w] = neg; }
  __syncthreads();
  if (t == 0) {
    partial[slot]         = red[0] + red[1] + red[2] + red[3];
    partial[NBLK2 + slot] = red[4] + red[5] + red[6] + red[7];
  }
}

// ---------------------------------------------------------------------------
// Kernel 2: 512 balanced blocks of pair tiles.
__global__ __launch_bounds__(256, 2) void pair_kernel(
    const unsigned short* __restrict__ Hf,
    const float4* __restrict__ PSL, float* __restrict__ partial) {
  __shared__ float4 sPi[128];
  __shared__ float4 sPj[128];
  __shared__ float red[8];

  const int bid = (int)blockIdx.x;
  if (bid < NOFF) {
    // strict upper-tri decode: bid -> (it, jt), it < jt; f(it)=31it-it(it-1)/2
    int it = (int)((63.0f - sqrtf(3969.0f - 8.0f * (float)bid)) * 0.5f);
    while (it > 0 && bid < 31 * it - it * (it - 1) / 2) --it;
    while (bid >= 31 * (it + 1) - (it + 1) * it / 2) ++it;
    const int jt = it + 1 + (bid - (31 * it - it * (it - 1) / 2));
    do_tile<false>(it, jt, bid, Hf, PSL, partial, sPi, sPj, red);
  } else {
    // 16 blocks each take two cheap diagonal tiles (~0.7x cost each)
    const int dd = bid - NOFF;
    do_tile<true>(2 * dd,     2 * dd,     NOFF + 2 * dd,     Hf, PSL, partial,
                  sPi, sPj, red);
    do_tile<true>(2 * dd + 1, 2 * dd + 1, NOFF + 2 * dd + 1, Hf, PSL, partial,
                  sPi, sPj, red);
  }
}

// ---------------------------------------------------------------------------
// Kernel 3: reduce per-tile slots, finalize 4 outputs.
// Full-grid sums = 2 * triangle sums (sym matrix, diag excluded).
__global__ __launch_bounds__(256) void finalize_kernel(
    const float* __restrict__ partial, float* __restrict__ out) {
  __shared__ float redp[4], redn[4];
  const int t = threadIdx.x;
  const int lane = t & 63, w = t >> 6;
  float p = 0.0f, n = 0.0f;
  for (int i = t; i < NBLK2; i += 256) {
    p += partial[i];
    n += partial[NBLK2 + i];
  }
  #pragma unroll
  for (int off = 32; off > 0; off >>= 1) {
    p += __shfl_down(p, off);
    n += __shfl_down(n, off);
  }
  if (lane == 0) { redp[w] = p; redn[w] = n; }
  __syncthreads();
  if (t == 0) {
    const float pos = 2.0f * (redp[0] + redp[1] + redp[2] + redp[3]);
    const float neg = 2.0f * (redn[0] + redn[1] + redn[2] + redn[3]);
    out[0] = pos * (1.0f / 16777216.0f);  // mean over N*N = 2^24
    out[1] = neg * (1.0f / 16777216.0f);
    out[2] = pos;
    out[3] = neg;
  }
}

extern "C" void kernel_launch(void* const* d_in, const int* in_sizes, int n_in,
                              void* d_out, int out_size, void* d_ws, size_t ws_size,
                              hipStream_t stream) {
  const float* mu = (const float*)d_in[0];
  const float* var = (const float*)d_in[1];
  const int* labels = (const int*)d_in[2];
  float* out = (float*)d_out;
  char* ws = (char*)d_ws;

  unsigned short* Hf = (unsigned short*)(ws + WS_H);
  float4* PSL = (float4*)(ws + WS_PSL);
  float* partial = (float*)(ws + WS_PART);

  precompute_kernel<<<dim3(N / 4), dim3(256), 0, stream>>>(mu, var, labels, Hf, PSL);
  pair_kernel<<<dim3(GRID2), dim3(256), 0, stream>>>(Hf, PSL, partial);
  finalize_kernel<<<dim3(1), dim3(256), 0, stream>>>(partial, out);
}